// Round 2
// baseline (490.161 us; speedup 1.0000x reference)
//
#include <hip/hip_runtime.h>
#include <hip/hip_bf16.h>
#include <math.h>

#define B_ 16
#define C_ 256
#define H_ 128
#define W_ 512
#define AF_ 256
#define HS_ 256

// ---------------- K0: pre-kernel (independent of features)
// blocks 0..255  : transpose convd_w (f,c,t) -> w2[(c*5+t)*256 + f]
// blocks 256..271: hv[b,f] = hidden[0,0,b,:] @ hid_w + hid_b
__global__ void k_pre(const float* __restrict__ convd_w,
                      const float* __restrict__ hidden,
                      const float* __restrict__ hid_w,
                      const float* __restrict__ hid_b,
                      float* __restrict__ w2, float* __restrict__ hv) {
  int bid = blockIdx.x, tid = threadIdx.x;
  if (bid < 256) {
    int f = bid;
#pragma unroll
    for (int q = 0; q < 5; ++q) {
      int r = q * 256 + tid;  // 0..1279 = c*5+t
      w2[(size_t)r * 256 + f] = convd_w[(size_t)f * 1280 + r];
    }
  } else {
    int b = bid - 256;
    const float* hh = hidden + b * HS_;
    float acc = hid_b[tid];
    for (int k = 0; k < HS_; ++k) acc = fmaf(hh[k], hid_w[k * AF_ + tid], acc);
    hv[b * AF_ + tid] = acc;
  }
}

// ---------------- K1: adaptive max pool (win=4) + dot dw_w -> h_feat[b,c,h]
// 4096 blocks x 256: each wave loops 32 contiguous rows of 512 floats.
__global__ void k_pool(const float* __restrict__ feat,
                       const float* __restrict__ dw_w,
                       const float* __restrict__ dw_b,
                       float* __restrict__ hf) {
  int gid = blockIdx.x * blockDim.x + threadIdx.x;
  int wv = gid >> 6;                 // 16384 waves
  int lane = threadIdx.x & 63;
  int base_row = wv * 32;
  float w0 = dw_w[lane], w1 = dw_w[lane + 64], wb = dw_b[0];
  const float4* f4 = reinterpret_cast<const float4*>(feat);
#pragma unroll 4
  for (int r = 0; r < 32; ++r) {
    const float4* row = f4 + (size_t)(base_row + r) * 128;
    float4 a = row[lane];
    float4 b = row[lane + 64];
    float m0 = fmaxf(fmaxf(a.x, a.y), fmaxf(a.z, a.w));
    float m1 = fmaxf(fmaxf(b.x, b.y), fmaxf(b.z, b.w));
    float p = m0 * w0 + m1 * w1;
#pragma unroll
    for (int off = 32; off > 0; off >>= 1) p += __shfl_down(p, off, 64);
    if (lane == 0) hf[base_row + r] = p + wb;
  }
}

// ---------------- K3: build s (tanh'd) + align. grid = B*(H/4), block 256 (f)
__global__ void k_sbuild(const float* __restrict__ pa,
                         const float* __restrict__ cv,
                         const float* __restrict__ hf,
                         const float* __restrict__ enc_w, const float* __restrict__ enc_b,
                         const float* __restrict__ conv_w, const float* __restrict__ conv_b,
                         const float* __restrict__ dcb_w, const float* __restrict__ dcb_b,
                         const float* __restrict__ hv,
                         const float* __restrict__ align_w, const float* __restrict__ align_b,
                         float* __restrict__ sbuf, float* __restrict__ alignv) {
  __shared__ float cat[2][H_];
  __shared__ float stats[4];     // mu0, inv_sigma0, mu1, inv_sigma1
  __shared__ float cbl[4][16];
  __shared__ float red[4][4];    // [wave][j]
  __shared__ float4 hfl[C_];     // h_feat[b, c, h0..h0+3]
  int bidx = blockIdx.x;
  int b = bidx >> 5;
  int h0 = (bidx & 31) * 4;
  int tid = threadIdx.x;

  // stage h_feat slice: 1024 floats
  {
    float* hl = reinterpret_cast<float*>(hfl);
#pragma unroll
    for (int q = 0; q < 4; ++q) {
      int t = tid + q * 256;
      int c = t >> 2, j = t & 3;
      hl[t] = hf[(size_t)(b * C_ + c) * H_ + h0 + j];
    }
  }
  if (tid < H_) {
    cat[0][tid] = pa[b * H_ + tid];
    float x = cv[b * H_ + tid];
    cat[1][tid] = fminf(fmaxf(x, 0.f), 1.f);
  }
  __syncthreads();
  if (tid < 2) {
    float s = 0.f, s2 = 0.f;
    for (int t = 0; t < H_; ++t) { float x = cat[tid][t]; s += x; s2 += x * x; }
    float mu = s / (float)H_;
    float var = s2 / (float)H_ - mu * mu;
    stats[tid * 2] = mu;
    stats[tid * 2 + 1] = rsqrtf(var + 1e-5f);
  }
  __syncthreads();
  {
    int ch = tid >> 7, t = tid & 127;     // all 256 threads
    cat[ch][t] = (cat[ch][t] - stats[ch * 2]) * stats[ch * 2 + 1];
  }
  __syncthreads();
  if (tid < 64) {            // cb[k, h0+j], kernel 15, pad 7
    int k = tid & 15, j = tid >> 4;
    int h = h0 + j;
    float acc = conv_b[k];
    for (int c2 = 0; c2 < 2; ++c2)
      for (int t = 0; t < 15; ++t) {
        int hh = h + t - 7;
        if (hh >= 0 && hh < H_) acc += cat[c2][hh] * conv_w[(k * 2 + c2) * 15 + t];
      }
    cbl[j][k] = acc;
  }
  __syncthreads();

  int f = tid;
  float base = enc_b[f] + dcb_b[f] + hv[b * AF_ + f];
  float acc[4];
#pragma unroll
  for (int j = 0; j < 4; ++j) {
    float a = base;
#pragma unroll
    for (int k = 0; k < 16; ++k) a = fmaf(cbl[j][k], dcb_w[k * AF_ + f], a);
    acc[j] = a;
  }
  for (int c = 0; c < C_; ++c) {
    float w = enc_w[c * AF_ + f];
    float4 h4 = hfl[c];               // LDS broadcast
    acc[0] = fmaf(h4.x, w, acc[0]);
    acc[1] = fmaf(h4.y, w, acc[1]);
    acc[2] = fmaf(h4.z, w, acc[2]);
    acc[3] = fmaf(h4.w, w, acc[3]);
  }
  float aw = align_w[f];
  int wvi = tid >> 6, lane = tid & 63;
#pragma unroll
  for (int j = 0; j < 4; ++j) {
    float s = tanhf(acc[j]);
    sbuf[(size_t)(b * H_ + h0 + j) * AF_ + f] = s;
    float v = s * aw;
#pragma unroll
    for (int off = 32; off > 0; off >>= 1) v += __shfl_down(v, off, 64);
    if (lane == 0) red[wvi][j] = v;
  }
  __syncthreads();
  if (tid < 4)
    alignv[b * H_ + h0 + tid] =
        red[0][tid] + red[1][tid] + red[2][tid] + red[3][tid] + align_b[0];
}

// ---------------- K4: softmax over H per batch. grid 16, block 128
__global__ void k_softmax(const float* __restrict__ alignv, float* __restrict__ attn) {
  __shared__ float redm[2], reds[2];
  int b = blockIdx.x, t = threadIdx.x;
  float v = alignv[b * H_ + t];
  float m = v;
#pragma unroll
  for (int off = 32; off > 0; off >>= 1) m = fmaxf(m, __shfl_down(m, off, 64));
  if ((t & 63) == 0) redm[t >> 6] = m;
  __syncthreads();
  float mm = fmaxf(redm[0], redm[1]);
  float e = expf(v - mm);
  float s = e;
#pragma unroll
  for (int off = 32; off > 0; off >>= 1) s += __shfl_down(s, off, 64);
  if ((t & 63) == 0) reds[t >> 6] = s;
  __syncthreads();
  attn[b * H_ + t] = e / (reds[0] + reds[1]);
}

// ---------------- K5 fused: blocks 0..255 decision conv; blocks 256..2303 context
// dconv: per block (b, h0 of 8 rows): conv K=5 pad=2 + relu + maxpool4 -> dpool
// ctx:   context[b,c,w] = sum_h feat[b,c,h,w]*attn[b,h]
__global__ void k_ctx_dconv(const float* __restrict__ feat, const float* __restrict__ attn,
                            const float* __restrict__ sbuf, const float* __restrict__ w2,
                            const float* __restrict__ convd_b,
                            float* __restrict__ dpool, float* __restrict__ ctx) {
  __shared__ float sw[12][AF_];   // dconv window; ctx path uses sw[0][0..127]
  int bidx = blockIdx.x;
  int tid = threadIdx.x;
  if (bidx < 256) {
    int b = bidx >> 4;
    int h0 = (bidx & 15) * 8;
    int f = tid;
    for (int rr = 0; rr < 12; ++rr) {          // rows h0-2 .. h0+9, zero padded
      int h = h0 - 2 + rr;
      sw[rr][f] = (h >= 0 && h < H_) ? sbuf[(size_t)(b * H_ + h) * AF_ + f] : 0.f;
    }
    __syncthreads();
    float acc[8];
#pragma unroll
    for (int j = 0; j < 8; ++j) acc[j] = 0.f;
    for (int c = 0; c < C_; ++c) {
      float sr[12];
#pragma unroll
      for (int rr = 0; rr < 12; ++rr) sr[rr] = sw[rr][c];   // LDS broadcast
      const float* wp = w2 + (size_t)c * 5 * 256 + f;
#pragma unroll
      for (int t = 0; t < 5; ++t) {
        float wvv = wp[t * 256];                            // coalesced, L2-resident
#pragma unroll
        for (int j = 0; j < 8; ++j) acc[j] = fmaf(sr[j + t], wvv, acc[j]);
      }
    }
    float bias = convd_b[f];
#pragma unroll
    for (int j = 0; j < 8; ++j) acc[j] = fmaxf(acc[j] + bias, 0.f);
    float p0 = fmaxf(fmaxf(acc[0], acc[1]), fmaxf(acc[2], acc[3]));
    float p1 = fmaxf(fmaxf(acc[4], acc[5]), fmaxf(acc[6], acc[7]));
    int m0 = (h0 >> 2);
    dpool[(size_t)(b * 32 + m0) * AF_ + f] = p0;
    dpool[(size_t)(b * 32 + m0 + 1) * AF_ + f] = p1;
  } else {
    int cb = bidx - 256;
    int b = cb >> 7;
    int c0 = (cb & 127) * 2;
    float* at = &sw[0][0];
    if (tid < H_) at[tid] = attn[b * H_ + tid];
    __syncthreads();
    int c = c0 + (tid >> 7);
    int wq = tid & 127;
    const float4* f4 = reinterpret_cast<const float4*>(feat) +
                       (size_t)(b * C_ + c) * H_ * (W_ / 4) + wq;
    float4 acc = make_float4(0.f, 0.f, 0.f, 0.f);
#pragma unroll 4
    for (int h = 0; h < H_; ++h) {
      float4 x = f4[(size_t)h * (W_ / 4)];
      float a = at[h];
      acc.x += x.x * a; acc.y += x.y * a; acc.z += x.z * a; acc.w += x.w * a;
    }
    reinterpret_cast<float4*>(ctx)[(size_t)(b * C_ + c) * (W_ / 4) + wq] = acc;
  }
}

// ---------------- K7: dh dot + relu, concat hh, dec matmul. grid 16, block 256
__global__ void k_decision(const float* __restrict__ dpool, const float* __restrict__ hidden,
                           const float* __restrict__ dh_w, const float* __restrict__ dh_b,
                           const float* __restrict__ dec_w, const float* __restrict__ dec_b,
                           float* __restrict__ dec_out) {
  __shared__ float ddl[AF_];
  __shared__ float red[4];
  int b = blockIdx.x, tid = threadIdx.x;
  float acc = dh_b[0];
  for (int m = 0; m < 32; ++m) acc = fmaf(dpool[(size_t)(b * 32 + m) * AF_ + tid], dh_w[m], acc);
  ddl[tid] = fmaxf(acc, 0.f);
  __syncthreads();
  int col = tid >> 7, kk = tid & 127;
  float a = 0.f;
#pragma unroll
  for (int q = 0; q < 4; ++q) {
    int idx = kk + 128 * q;                  // 0..511 over concat [hh(256), dd(256)]
    float x = (idx < 256) ? hidden[b * HS_ + idx] : ddl[idx - 256];
    a = fmaf(x, dec_w[idx * 2 + col], a);
  }
#pragma unroll
  for (int off = 32; off > 0; off >>= 1) a += __shfl_down(a, off, 64);
  if ((tid & 63) == 0) red[tid >> 6] = a;
  __syncthreads();
  if (tid < 2) dec_out[b * 2 + tid] = red[tid * 2] + red[tid * 2 + 1] + dec_b[tid];
}

extern "C" void kernel_launch(void* const* d_in, const int* in_sizes, int n_in,
                              void* d_out, int out_size, void* d_ws, size_t ws_size,
                              hipStream_t stream) {
  const float* feat    = (const float*)d_in[0];
  const float* pa      = (const float*)d_in[1];
  const float* cv      = (const float*)d_in[2];
  const float* hidden  = (const float*)d_in[3];
  const float* dw_w    = (const float*)d_in[4];
  const float* dw_b    = (const float*)d_in[5];
  const float* enc_w   = (const float*)d_in[6];
  const float* enc_b   = (const float*)d_in[7];
  const float* conv_w  = (const float*)d_in[8];
  const float* conv_b  = (const float*)d_in[9];
  const float* dcb_w   = (const float*)d_in[10];
  const float* dcb_b   = (const float*)d_in[11];
  const float* hid_w   = (const float*)d_in[12];
  const float* hid_b   = (const float*)d_in[13];
  const float* align_w = (const float*)d_in[14];
  const float* align_b = (const float*)d_in[15];
  const float* convd_w = (const float*)d_in[16];
  const float* convd_b = (const float*)d_in[17];
  const float* dh_w    = (const float*)d_in[18];
  const float* dh_b    = (const float*)d_in[19];
  const float* dec_w   = (const float*)d_in[20];
  const float* dec_b   = (const float*)d_in[21];

  float* out  = (float*)d_out;
  float* ctx  = out;                          // (B,C,W) = 2,097,152 floats
  float* attn = out + 2097152;                // (B,H)   = 2048
  float* dec  = out + 2097152 + 2048;         // (B,2)   = 32

  // All scratch in d_ws (>=4GB). Every buffer fully rewritten each call.
  float* ws     = (float*)d_ws;
  float* hf     = ws;                         // 524288  h_feat (B,C,H)
  float* sbuf   = ws + 524288;                // 524288  s (B,H,AF) post-tanh
  float* dpool  = ws + 1048576;               // 131072  (B,32,AF)
  float* hv     = ws + 1179648;               // 4096    (B,AF)
  float* alignv = ws + 1183744;               // 2048    (B,H)
  float* w2     = ws + 1185792;               // 327680  transposed convd_w

  k_pre<<<272, 256, 0, stream>>>(convd_w, hidden, hid_w, hid_b, w2, hv);
  k_pool<<<4096, 256, 0, stream>>>(feat, dw_w, dw_b, hf);
  k_sbuild<<<512, 256, 0, stream>>>(pa, cv, hf, enc_w, enc_b, conv_w, conv_b,
                                    dcb_w, dcb_b, hv, align_w, align_b, sbuf, alignv);
  k_softmax<<<16, 128, 0, stream>>>(alignv, attn);
  k_ctx_dconv<<<2304, 256, 0, stream>>>(feat, attn, sbuf, w2, convd_b, dpool, ctx);
  k_decision<<<16, 256, 0, stream>>>(dpool, hidden, dh_w, dh_b, dec_w, dec_b, dec);
}

// Round 3
// 462.475 us; speedup vs baseline: 1.0599x; 1.0599x over previous
//
#include <hip/hip_runtime.h>
#include <hip/hip_bf16.h>
#include <math.h>

#define B_ 16
#define C_ 256
#define H_ 128
#define W_ 512
#define AF_ 256
#define HS_ 256

// ---------------- K0: pre-kernel (independent of features)
// blocks 0..255  : transpose convd_w (f,c,t) -> w2[(c*5+t)*256 + f]
// blocks 256..271: hv[b,f] = hidden[0,0,b,:] @ hid_w + hid_b
__global__ void k_pre(const float* __restrict__ convd_w,
                      const float* __restrict__ hidden,
                      const float* __restrict__ hid_w,
                      const float* __restrict__ hid_b,
                      float* __restrict__ w2, float* __restrict__ hv) {
  int bid = blockIdx.x, tid = threadIdx.x;
  if (bid < 256) {
    int f = bid;
#pragma unroll
    for (int q = 0; q < 5; ++q) {
      int r = q * 256 + tid;  // 0..1279 = c*5+t
      w2[(size_t)r * 256 + f] = convd_w[(size_t)f * 1280 + r];
    }
  } else {
    int b = bid - 256;
    const float* hh = hidden + b * HS_;
    float acc = hid_b[tid];
    for (int k = 0; k < HS_; ++k) acc = fmaf(hh[k], hid_w[k * AF_ + tid], acc);
    hv[b * AF_ + tid] = acc;
  }
}

// ---------------- K1: adaptive max pool (win=4) + dot dw_w -> h_feat[b,c,h]
// 32768 blocks x 256: each wave handles 4 consecutive rows of 512 floats.
__global__ void k_pool(const float* __restrict__ feat,
                       const float* __restrict__ dw_w,
                       const float* __restrict__ dw_b,
                       float* __restrict__ hf) {
  int gid = blockIdx.x * blockDim.x + threadIdx.x;
  int wv = gid >> 6;                 // 131072 waves
  int lane = threadIdx.x & 63;
  int base_row = wv * 4;
  float w0 = dw_w[lane], w1 = dw_w[lane + 64], wb = dw_b[0];
  const float4* f4 = reinterpret_cast<const float4*>(feat);
#pragma unroll
  for (int r = 0; r < 4; ++r) {
    const float4* row = f4 + (size_t)(base_row + r) * 128;
    float4 a = row[lane];
    float4 b = row[lane + 64];
    float m0 = fmaxf(fmaxf(a.x, a.y), fmaxf(a.z, a.w));
    float m1 = fmaxf(fmaxf(b.x, b.y), fmaxf(b.z, b.w));
    float p = m0 * w0 + m1 * w1;
#pragma unroll
    for (int off = 32; off > 0; off >>= 1) p += __shfl_down(p, off, 64);
    if (lane == 0) hf[base_row + r] = p + wb;
  }
}

// ---------------- K3: build s (tanh'd) + align. grid = B*(H/4), block 256 (f)
__global__ void k_sbuild(const float* __restrict__ pa,
                         const float* __restrict__ cv,
                         const float* __restrict__ hf,
                         const float* __restrict__ enc_w, const float* __restrict__ enc_b,
                         const float* __restrict__ conv_w, const float* __restrict__ conv_b,
                         const float* __restrict__ dcb_w, const float* __restrict__ dcb_b,
                         const float* __restrict__ hv,
                         const float* __restrict__ align_w, const float* __restrict__ align_b,
                         float* __restrict__ sbuf, float* __restrict__ alignv) {
  __shared__ float cat[2][H_];
  __shared__ float stats[4];     // mu0, inv_sigma0, mu1, inv_sigma1
  __shared__ float cbl[4][16];
  __shared__ float red[4][4];    // [wave][j]
  int bidx = blockIdx.x;
  int b = bidx >> 5;
  int h0 = (bidx & 31) * 4;
  int tid = threadIdx.x;

  if (tid < H_) {
    cat[0][tid] = pa[b * H_ + tid];
    float x = cv[b * H_ + tid];
    cat[1][tid] = fminf(fmaxf(x, 0.f), 1.f);
  }
  __syncthreads();
  if (tid < 2) {
    float s = 0.f, s2 = 0.f;
    for (int t = 0; t < H_; ++t) { float x = cat[tid][t]; s += x; s2 += x * x; }
    float mu = s / (float)H_;
    float var = s2 / (float)H_ - mu * mu;
    stats[tid * 2] = mu;
    stats[tid * 2 + 1] = rsqrtf(var + 1e-5f);
  }
  __syncthreads();
  {
    int ch = tid >> 7, t = tid & 127;     // all 256 threads
    cat[ch][t] = (cat[ch][t] - stats[ch * 2]) * stats[ch * 2 + 1];
  }
  __syncthreads();
  if (tid < 64) {            // cb[k, h0+j], kernel 15, pad 7
    int k = tid & 15, j = tid >> 4;
    int h = h0 + j;
    float acc = conv_b[k];
    for (int c2 = 0; c2 < 2; ++c2)
      for (int t = 0; t < 15; ++t) {
        int hh = h + t - 7;
        if (hh >= 0 && hh < H_) acc += cat[c2][hh] * conv_w[(k * 2 + c2) * 15 + t];
      }
    cbl[j][k] = acc;
  }
  __syncthreads();

  int f = tid;
  float base = enc_b[f] + dcb_b[f] + hv[b * AF_ + f];
  float acc[4];
#pragma unroll
  for (int j = 0; j < 4; ++j) {
    float a = base;
#pragma unroll
    for (int k = 0; k < 16; ++k) a = fmaf(cbl[j][k], dcb_w[k * AF_ + f], a);
    acc[j] = a;
  }
  const float* hfb = hf + (size_t)(b * C_) * H_ + h0;   // wave-uniform scalar loads
  for (int c = 0; c < C_; ++c) {
    float w = enc_w[c * AF_ + f];
#pragma unroll
    for (int j = 0; j < 4; ++j) acc[j] = fmaf(hfb[c * H_ + j], w, acc[j]);
  }
  float aw = align_w[f];
  int wvi = tid >> 6, lane = tid & 63;
#pragma unroll
  for (int j = 0; j < 4; ++j) {
    float s = tanhf(acc[j]);
    sbuf[(size_t)(b * H_ + h0 + j) * AF_ + f] = s;
    float v = s * aw;
#pragma unroll
    for (int off = 32; off > 0; off >>= 1) v += __shfl_down(v, off, 64);
    if (lane == 0) red[wvi][j] = v;
  }
  __syncthreads();
  if (tid < 4)
    alignv[b * H_ + h0 + tid] =
        red[0][tid] + red[1][tid] + red[2][tid] + red[3][tid] + align_b[0];
}

// ---------------- K4: softmax over H per batch. grid 16, block 128
__global__ void k_softmax(const float* __restrict__ alignv, float* __restrict__ attn) {
  __shared__ float redm[2], reds[2];
  int b = blockIdx.x, t = threadIdx.x;
  float v = alignv[b * H_ + t];
  float m = v;
#pragma unroll
  for (int off = 32; off > 0; off >>= 1) m = fmaxf(m, __shfl_down(m, off, 64));
  if ((t & 63) == 0) redm[t >> 6] = m;
  __syncthreads();
  float mm = fmaxf(redm[0], redm[1]);
  float e = expf(v - mm);
  float s = e;
#pragma unroll
  for (int off = 32; off > 0; off >>= 1) s += __shfl_down(s, off, 64);
  if ((t & 63) == 0) reds[t >> 6] = s;
  __syncthreads();
  attn[b * H_ + t] = e / (reds[0] + reds[1]);
}

// ---------------- K6: decision conv (K=5,pad=2) + relu + maxpool4 -> dpool[b,m,f]
// grid = B*16 (8 h each), block 512: f = tid&255, c-half = tid>>8
__global__ void k_dconv(const float* __restrict__ sbuf, const float* __restrict__ w2,
                        const float* __restrict__ convd_b, float* __restrict__ dpool) {
  __shared__ float sw[12][AF_];
  __shared__ float part[8][AF_];
  int bidx = blockIdx.x;
  int b = bidx >> 4;
  int h0 = (bidx & 15) * 8;
  int tid = threadIdx.x;
  int f = tid & 255;
  int chalf = tid >> 8;
  for (int rr = chalf; rr < 12; rr += 2) {     // rows h0-2 .. h0+9, zero padded
    int h = h0 - 2 + rr;
    sw[rr][f] = (h >= 0 && h < H_) ? sbuf[(size_t)(b * H_ + h) * AF_ + f] : 0.f;
  }
  __syncthreads();
  float acc[8];
#pragma unroll
  for (int j = 0; j < 8; ++j) acc[j] = 0.f;
  int cstart = chalf * 128;
  for (int c = cstart; c < cstart + 128; ++c) {
    float sr[12];
#pragma unroll
    for (int rr = 0; rr < 12; ++rr) sr[rr] = sw[rr][c];   // LDS broadcast
    const float* wp = w2 + (size_t)c * 5 * 256 + f;
#pragma unroll
    for (int t = 0; t < 5; ++t) {
      float wv = wp[t * 256];                             // coalesced, L2-resident
#pragma unroll
      for (int j = 0; j < 8; ++j) acc[j] = fmaf(sr[j + t], wv, acc[j]);
    }
  }
  if (chalf == 1) {
#pragma unroll
    for (int j = 0; j < 8; ++j) part[j][f] = acc[j];
  }
  __syncthreads();
  if (chalf == 0) {
    float bias = convd_b[f];
#pragma unroll
    for (int j = 0; j < 8; ++j) acc[j] = fmaxf(acc[j] + part[j][f] + bias, 0.f);
    float p0 = fmaxf(fmaxf(acc[0], acc[1]), fmaxf(acc[2], acc[3]));
    float p1 = fmaxf(fmaxf(acc[4], acc[5]), fmaxf(acc[6], acc[7]));
    int m0 = h0 >> 2;
    dpool[(size_t)(b * 32 + m0) * AF_ + f] = p0;
    dpool[(size_t)(b * 32 + m0 + 1) * AF_ + f] = p1;
  }
}

// ---------------- K7: dh dot + relu, concat hh, dec matmul. grid 16, block 256
__global__ void k_decision(const float* __restrict__ dpool, const float* __restrict__ hidden,
                           const float* __restrict__ dh_w, const float* __restrict__ dh_b,
                           const float* __restrict__ dec_w, const float* __restrict__ dec_b,
                           float* __restrict__ dec_out) {
  __shared__ float ddl[AF_];
  __shared__ float red[4];
  int b = blockIdx.x, tid = threadIdx.x;
  float acc = dh_b[0];
  for (int m = 0; m < 32; ++m) acc = fmaf(dpool[(size_t)(b * 32 + m) * AF_ + tid], dh_w[m], acc);
  ddl[tid] = fmaxf(acc, 0.f);
  __syncthreads();
  int col = tid >> 7, kk = tid & 127;
  float a = 0.f;
#pragma unroll
  for (int q = 0; q < 4; ++q) {
    int idx = kk + 128 * q;                  // 0..511 over concat [hh(256), dd(256)]
    float x = (idx < 256) ? hidden[b * HS_ + idx] : ddl[idx - 256];
    a = fmaf(x, dec_w[idx * 2 + col], a);
  }
#pragma unroll
  for (int off = 32; off > 0; off >>= 1) a += __shfl_down(a, off, 64);
  if ((tid & 63) == 0) red[tid >> 6] = a;
  __syncthreads();
  if (tid < 2) dec_out[b * 2 + tid] = red[tid * 2] + red[tid * 2 + 1] + dec_b[tid];
}

// ---------------- K5: context[b,c,w] = sum_h feat[b,c,h,w]*attn[b,h]
// grid = B*C/2, block 256: 2 c-rows per block, float4 per thread
__global__ void k_context(const float* __restrict__ feat, const float* __restrict__ attn,
                          float* __restrict__ ctx) {
  __shared__ float at[H_];
  int bidx = blockIdx.x;
  int b = bidx >> 7;
  int c0 = (bidx & 127) * 2;
  int tid = threadIdx.x;
  if (tid < H_) at[tid] = attn[b * H_ + tid];
  __syncthreads();
  int c = c0 + (tid >> 7);
  int wq = tid & 127;
  const float4* f4 = reinterpret_cast<const float4*>(feat) +
                     (size_t)(b * C_ + c) * H_ * (W_ / 4) + wq;
  float4 acc = make_float4(0.f, 0.f, 0.f, 0.f);
  for (int h = 0; h < H_; ++h) {
    float4 x = f4[(size_t)h * (W_ / 4)];
    float a = at[h];
    acc.x += x.x * a; acc.y += x.y * a; acc.z += x.z * a; acc.w += x.w * a;
  }
  reinterpret_cast<float4*>(ctx)[(size_t)(b * C_ + c) * (W_ / 4) + wq] = acc;
}

extern "C" void kernel_launch(void* const* d_in, const int* in_sizes, int n_in,
                              void* d_out, int out_size, void* d_ws, size_t ws_size,
                              hipStream_t stream) {
  const float* feat    = (const float*)d_in[0];
  const float* pa      = (const float*)d_in[1];
  const float* cv      = (const float*)d_in[2];
  const float* hidden  = (const float*)d_in[3];
  const float* dw_w    = (const float*)d_in[4];
  const float* dw_b    = (const float*)d_in[5];
  const float* enc_w   = (const float*)d_in[6];
  const float* enc_b   = (const float*)d_in[7];
  const float* conv_w  = (const float*)d_in[8];
  const float* conv_b  = (const float*)d_in[9];
  const float* dcb_w   = (const float*)d_in[10];
  const float* dcb_b   = (const float*)d_in[11];
  const float* hid_w   = (const float*)d_in[12];
  const float* hid_b   = (const float*)d_in[13];
  const float* align_w = (const float*)d_in[14];
  const float* align_b = (const float*)d_in[15];
  const float* convd_w = (const float*)d_in[16];
  const float* convd_b = (const float*)d_in[17];
  const float* dh_w    = (const float*)d_in[18];
  const float* dh_b    = (const float*)d_in[19];
  const float* dec_w   = (const float*)d_in[20];
  const float* dec_b   = (const float*)d_in[21];

  float* out  = (float*)d_out;
  float* ctx  = out;                          // (B,C,W) = 2,097,152 floats
  float* attn = out + 2097152;                // (B,H)   = 2048
  float* dec  = out + 2097152 + 2048;         // (B,2)   = 32

  // Scratch lives inside the ctx region; k_context (last) overwrites it fully.
  float* hf     = ctx;                        // 524288  h_feat (B,C,H)
  float* sbuf   = ctx + 524288;               // 524288  s (B,H,AF) post-tanh
  float* dpool  = ctx + 1048576;              // 131072  (B,32,AF)
  float* hv     = ctx + 1179648;              // 4096    (B,AF)
  float* alignv = ctx + 1183744;              // 2048    (B,H)
  float* w2     = ctx + 1185792;              // 327680  transposed convd_w
  // total scratch end: 1,513,472 < 2,097,152  -- fits

  k_pre<<<272, 256, 0, stream>>>(convd_w, hidden, hid_w, hid_b, w2, hv);
  k_pool<<<32768, 256, 0, stream>>>(feat, dw_w, dw_b, hf);
  k_sbuild<<<512, 256, 0, stream>>>(pa, cv, hf, enc_w, enc_b, conv_w, conv_b,
                                    dcb_w, dcb_b, hv, align_w, align_b, sbuf, alignv);
  k_softmax<<<16, 128, 0, stream>>>(alignv, attn);
  k_dconv<<<256, 512, 0, stream>>>(sbuf, w2, convd_b, dpool);
  k_decision<<<16, 256, 0, stream>>>(dpool, hidden, dh_w, dh_b, dec_w, dec_b, dec);
  k_context<<<2048, 256, 0, stream>>>(feat, attn, ctx);
}

// Round 4
// 439.608 us; speedup vs baseline: 1.1150x; 1.0520x over previous
//
#include <hip/hip_runtime.h>
#include <hip/hip_bf16.h>
#include <math.h>

#define B_ 16
#define C_ 256
#define H_ 128
#define W_ 512
#define AF_ 256
#define HS_ 256

// ---------------- K0: pre-kernel (independent of features)
// blocks 0..255  : transpose convd_w (f,c,t) -> w2[(c*5+t)*256 + f]
// blocks 256..271: hv[b,f] = hidden[0,0,b,:] @ hid_w + hid_b
__global__ void k_pre(const float* __restrict__ convd_w,
                      const float* __restrict__ hidden,
                      const float* __restrict__ hid_w,
                      const float* __restrict__ hid_b,
                      float* __restrict__ w2, float* __restrict__ hv) {
  int bid = blockIdx.x, tid = threadIdx.x;
  if (bid < 256) {
    int f = bid;
#pragma unroll
    for (int q = 0; q < 5; ++q) {
      int r = q * 256 + tid;  // 0..1279 = c*5+t
      w2[(size_t)r * 256 + f] = convd_w[(size_t)f * 1280 + r];
    }
  } else {
    int b = bid - 256;
    const float* hh = hidden + b * HS_;
    float acc = hid_b[tid];
    for (int k = 0; k < HS_; ++k) acc = fmaf(hh[k], hid_w[k * AF_ + tid], acc);
    hv[b * AF_ + tid] = acc;
  }
}

// ---------------- K1: adaptive max pool (win=4) + dot dw_w -> h_feat[b,c,h]
// one wave per row of 512 floats; lane reads 2 float4 windows. (1 row/wave:
// measured best — multi-row per wave regressed: R2 +47us, R3 +19us)
__global__ void k_pool(const float* __restrict__ feat,
                       const float* __restrict__ dw_w,
                       const float* __restrict__ dw_b,
                       float* __restrict__ hf) {
  int gid = blockIdx.x * blockDim.x + threadIdx.x;
  int wid = gid >> 6;            // row id, grid sized exactly: 524288 waves
  int lane = threadIdx.x & 63;
  const float4* row = reinterpret_cast<const float4*>(feat) + (size_t)wid * 128;
  float4 a = row[lane];
  float4 b = row[lane + 64];
  float m0 = fmaxf(fmaxf(a.x, a.y), fmaxf(a.z, a.w));
  float m1 = fmaxf(fmaxf(b.x, b.y), fmaxf(b.z, b.w));
  float p = m0 * dw_w[lane] + m1 * dw_w[lane + 64];
#pragma unroll
  for (int off = 32; off > 0; off >>= 1) p += __shfl_down(p, off, 64);
  if (lane == 0) hf[wid] = p + dw_b[0];
}

// ---------------- K3: build s (tanh'd) + align. grid = B*(H/4), block 256 (f)
__global__ void k_sbuild(const float* __restrict__ pa,
                         const float* __restrict__ cv,
                         const float* __restrict__ hf,
                         const float* __restrict__ enc_w, const float* __restrict__ enc_b,
                         const float* __restrict__ conv_w, const float* __restrict__ conv_b,
                         const float* __restrict__ dcb_w, const float* __restrict__ dcb_b,
                         const float* __restrict__ hv,
                         const float* __restrict__ align_w, const float* __restrict__ align_b,
                         float* __restrict__ sbuf, float* __restrict__ alignv) {
  __shared__ float cat[2][H_];
  __shared__ float stats[4];     // mu0, inv_sigma0, mu1, inv_sigma1
  __shared__ float cbl[4][16];
  __shared__ float red[4][4];    // [wave][j]
  int bidx = blockIdx.x;
  int b = bidx >> 5;
  int h0 = (bidx & 31) * 4;
  int tid = threadIdx.x;

  if (tid < H_) {
    cat[0][tid] = pa[b * H_ + tid];
    float x = cv[b * H_ + tid];
    cat[1][tid] = fminf(fmaxf(x, 0.f), 1.f);
  }
  __syncthreads();
  if (tid < 2) {
    float s = 0.f, s2 = 0.f;
    for (int t = 0; t < H_; ++t) { float x = cat[tid][t]; s += x; s2 += x * x; }
    float mu = s / (float)H_;
    float var = s2 / (float)H_ - mu * mu;
    stats[tid * 2] = mu;
    stats[tid * 2 + 1] = rsqrtf(var + 1e-5f);
  }
  __syncthreads();
  {
    int ch = tid >> 7, t = tid & 127;     // all 256 threads
    cat[ch][t] = (cat[ch][t] - stats[ch * 2]) * stats[ch * 2 + 1];
  }
  __syncthreads();
  if (tid < 64) {            // cb[k, h0+j], kernel 15, pad 7
    int k = tid & 15, j = tid >> 4;
    int h = h0 + j;
    float acc = conv_b[k];
    for (int c2 = 0; c2 < 2; ++c2)
      for (int t = 0; t < 15; ++t) {
        int hh = h + t - 7;
        if (hh >= 0 && hh < H_) acc += cat[c2][hh] * conv_w[(k * 2 + c2) * 15 + t];
      }
    cbl[j][k] = acc;
  }
  __syncthreads();

  int f = tid;
  float base = enc_b[f] + dcb_b[f] + hv[b * AF_ + f];
  float acc[4];
#pragma unroll
  for (int j = 0; j < 4; ++j) {
    float a = base;
#pragma unroll
    for (int k = 0; k < 16; ++k) a = fmaf(cbl[j][k], dcb_w[k * AF_ + f], a);
    acc[j] = a;
  }
  const float* hfb = hf + (size_t)(b * C_) * H_ + h0;   // wave-uniform scalar loads
  for (int c = 0; c < C_; ++c) {
    float w = enc_w[c * AF_ + f];
#pragma unroll
    for (int j = 0; j < 4; ++j) acc[j] = fmaf(hfb[c * H_ + j], w, acc[j]);
  }
  float aw = align_w[f];
  int wvi = tid >> 6, lane = tid & 63;
#pragma unroll
  for (int j = 0; j < 4; ++j) {
    float s = tanhf(acc[j]);
    sbuf[(size_t)(b * H_ + h0 + j) * AF_ + f] = s;
    float v = s * aw;
#pragma unroll
    for (int off = 32; off > 0; off >>= 1) v += __shfl_down(v, off, 64);
    if (lane == 0) red[wvi][j] = v;
  }
  __syncthreads();
  if (tid < 4)
    alignv[b * H_ + h0 + tid] =
        red[0][tid] + red[1][tid] + red[2][tid] + red[3][tid] + align_b[0];
}

// ---------------- K4: softmax over H per batch. grid 16, block 128
__global__ void k_softmax(const float* __restrict__ alignv, float* __restrict__ attn) {
  __shared__ float redm[2], reds[2];
  int b = blockIdx.x, t = threadIdx.x;
  float v = alignv[b * H_ + t];
  float m = v;
#pragma unroll
  for (int off = 32; off > 0; off >>= 1) m = fmaxf(m, __shfl_down(m, off, 64));
  if ((t & 63) == 0) redm[t >> 6] = m;
  __syncthreads();
  float mm = fmaxf(redm[0], redm[1]);
  float e = expf(v - mm);
  float s = e;
#pragma unroll
  for (int off = 32; off > 0; off >>= 1) s += __shfl_down(s, off, 64);
  if ((t & 63) == 0) reds[t >> 6] = s;
  __syncthreads();
  attn[b * H_ + t] = e / (reds[0] + reds[1]);
}

// ---------------- K6: decision conv (K=5,pad=2) + relu + maxpool4 -> dpool[b,m,f]
// grid = B*16 (8 h each), block 512: f = tid&255, c-half = tid>>8
__global__ void k_dconv(const float* __restrict__ sbuf, const float* __restrict__ w2,
                        const float* __restrict__ convd_b, float* __restrict__ dpool) {
  __shared__ float sw[12][AF_];
  __shared__ float part[8][AF_];
  int bidx = blockIdx.x;
  int b = bidx >> 4;
  int h0 = (bidx & 15) * 8;
  int tid = threadIdx.x;
  int f = tid & 255;
  int chalf = tid >> 8;
  for (int rr = chalf; rr < 12; rr += 2) {     // rows h0-2 .. h0+9, zero padded
    int h = h0 - 2 + rr;
    sw[rr][f] = (h >= 0 && h < H_) ? sbuf[(size_t)(b * H_ + h) * AF_ + f] : 0.f;
  }
  __syncthreads();
  float acc[8];
#pragma unroll
  for (int j = 0; j < 8; ++j) acc[j] = 0.f;
  int cstart = chalf * 128;
  for (int c = cstart; c < cstart + 128; ++c) {
    float sr[12];
#pragma unroll
    for (int rr = 0; rr < 12; ++rr) sr[rr] = sw[rr][c];   // LDS broadcast
    const float* wp = w2 + (size_t)c * 5 * 256 + f;
#pragma unroll
    for (int t = 0; t < 5; ++t) {
      float wv = wp[t * 256];                             // coalesced, L2-resident
#pragma unroll
      for (int j = 0; j < 8; ++j) acc[j] = fmaf(sr[j + t], wv, acc[j]);
    }
  }
  if (chalf == 1) {
#pragma unroll
    for (int j = 0; j < 8; ++j) part[j][f] = acc[j];
  }
  __syncthreads();
  if (chalf == 0) {
    float bias = convd_b[f];
#pragma unroll
    for (int j = 0; j < 8; ++j) acc[j] = fmaxf(acc[j] + part[j][f] + bias, 0.f);
    float p0 = fmaxf(fmaxf(acc[0], acc[1]), fmaxf(acc[2], acc[3]));
    float p1 = fmaxf(fmaxf(acc[4], acc[5]), fmaxf(acc[6], acc[7]));
    int m0 = h0 >> 2;
    dpool[(size_t)(b * 32 + m0) * AF_ + f] = p0;
    dpool[(size_t)(b * 32 + m0 + 1) * AF_ + f] = p1;
  }
}

// ---------------- K7: dh dot + relu, concat hh, dec matmul. grid 16, block 256
__global__ void k_decision(const float* __restrict__ dpool, const float* __restrict__ hidden,
                           const float* __restrict__ dh_w, const float* __restrict__ dh_b,
                           const float* __restrict__ dec_w, const float* __restrict__ dec_b,
                           float* __restrict__ dec_out) {
  __shared__ float ddl[AF_];
  __shared__ float red[4];
  int b = blockIdx.x, tid = threadIdx.x;
  float acc = dh_b[0];
  for (int m = 0; m < 32; ++m) acc = fmaf(dpool[(size_t)(b * 32 + m) * AF_ + tid], dh_w[m], acc);
  ddl[tid] = fmaxf(acc, 0.f);
  __syncthreads();
  int col = tid >> 7, kk = tid & 127;
  float a = 0.f;
#pragma unroll
  for (int q = 0; q < 4; ++q) {
    int idx = kk + 128 * q;                  // 0..511 over concat [hh(256), dd(256)]
    float x = (idx < 256) ? hidden[b * HS_ + idx] : ddl[idx - 256];
    a = fmaf(x, dec_w[idx * 2 + col], a);
  }
#pragma unroll
  for (int off = 32; off > 0; off >>= 1) a += __shfl_down(a, off, 64);
  if ((tid & 63) == 0) red[tid >> 6] = a;
  __syncthreads();
  if (tid < 2) dec_out[b * 2 + tid] = red[tid * 2] + red[tid * 2 + 1] + dec_b[tid];
}

// ---------------- K5: context[b,c,w] = sum_h feat[b,c,h,w]*attn[b,h]
// grid = B*C/2, block 256: 2 c-rows per block, float4 per thread.
// REVERSED block->(b,c) mapping: k_pool streamed feat front-to-back, so L3
// (256MB) holds the tail; consuming the tail first converts it to hits.
__global__ void k_context(const float* __restrict__ feat, const float* __restrict__ attn,
                          float* __restrict__ ctx) {
  __shared__ float at[H_];
  int cb = 2047 - blockIdx.x;          // reverse traversal for L3 reuse
  int b = cb >> 7;
  int c0 = (cb & 127) * 2;
  int tid = threadIdx.x;
  if (tid < H_) at[tid] = attn[b * H_ + tid];
  __syncthreads();
  int c = c0 + (tid >> 7);
  int wq = tid & 127;
  const float4* f4 = reinterpret_cast<const float4*>(feat) +
                     (size_t)(b * C_ + c) * H_ * (W_ / 4) + wq;
  float4 acc = make_float4(0.f, 0.f, 0.f, 0.f);
  for (int h = 0; h < H_; ++h) {
    float4 x = f4[(size_t)h * (W_ / 4)];
    float a = at[h];
    acc.x += x.x * a; acc.y += x.y * a; acc.z += x.z * a; acc.w += x.w * a;
  }
  reinterpret_cast<float4*>(ctx)[(size_t)(b * C_ + c) * (W_ / 4) + wq] = acc;
}

extern "C" void kernel_launch(void* const* d_in, const int* in_sizes, int n_in,
                              void* d_out, int out_size, void* d_ws, size_t ws_size,
                              hipStream_t stream) {
  const float* feat    = (const float*)d_in[0];
  const float* pa      = (const float*)d_in[1];
  const float* cv      = (const float*)d_in[2];
  const float* hidden  = (const float*)d_in[3];
  const float* dw_w    = (const float*)d_in[4];
  const float* dw_b    = (const float*)d_in[5];
  const float* enc_w   = (const float*)d_in[6];
  const float* enc_b   = (const float*)d_in[7];
  const float* conv_w  = (const float*)d_in[8];
  const float* conv_b  = (const float*)d_in[9];
  const float* dcb_w   = (const float*)d_in[10];
  const float* dcb_b   = (const float*)d_in[11];
  const float* hid_w   = (const float*)d_in[12];
  const float* hid_b   = (const float*)d_in[13];
  const float* align_w = (const float*)d_in[14];
  const float* align_b = (const float*)d_in[15];
  const float* convd_w = (const float*)d_in[16];
  const float* convd_b = (const float*)d_in[17];
  const float* dh_w    = (const float*)d_in[18];
  const float* dh_b    = (const float*)d_in[19];
  const float* dec_w   = (const float*)d_in[20];
  const float* dec_b   = (const float*)d_in[21];

  float* out  = (float*)d_out;
  float* ctx  = out;                          // (B,C,W) = 2,097,152 floats
  float* attn = out + 2097152;                // (B,H)   = 2048
  float* dec  = out + 2097152 + 2048;         // (B,2)   = 32

  // Scratch lives inside the ctx region; k_context (last) overwrites it fully.
  float* hf     = ctx;                        // 524288  h_feat (B,C,H)
  float* sbuf   = ctx + 524288;               // 524288  s (B,H,AF) post-tanh
  float* dpool  = ctx + 1048576;              // 131072  (B,32,AF)
  float* hv     = ctx + 1179648;              // 4096    (B,AF)
  float* alignv = ctx + 1183744;              // 2048    (B,H)
  float* w2     = ctx + 1185792;              // 327680  transposed convd_w
  // total scratch end: 1,513,472 < 2,097,152  -- fits

  k_pre<<<272, 256, 0, stream>>>(convd_w, hidden, hid_w, hid_b, w2, hv);
  k_pool<<<131072, 256, 0, stream>>>(feat, dw_w, dw_b, hf);
  k_sbuild<<<512, 256, 0, stream>>>(pa, cv, hf, enc_w, enc_b, conv_w, conv_b,
                                    dcb_w, dcb_b, hv, align_w, align_b, sbuf, alignv);
  k_softmax<<<16, 128, 0, stream>>>(alignv, attn);
  k_dconv<<<256, 512, 0, stream>>>(sbuf, w2, convd_b, dpool);
  k_decision<<<16, 256, 0, stream>>>(dpool, hidden, dh_w, dh_b, dec_w, dec_b, dec);
  k_context<<<2048, 256, 0, stream>>>(feat, attn, ctx);
}

// Round 5
// 394.660 us; speedup vs baseline: 1.2420x; 1.1139x over previous
//
#include <hip/hip_runtime.h>
#include <hip/hip_bf16.h>
#include <math.h>

#define B_ 16
#define C_ 256
#define H_ 128
#define W_ 512
#define AF_ 256
#define HS_ 256

typedef float f4v __attribute__((ext_vector_type(4)));

// ---------------- L1: pre (w2 transpose + hv) fused with pool.
// bid 0..255   : transpose convd_w (f,c,t) -> w2[(c*5+t)*256 + f]
// bid 256..271 : hv[b,f] = hidden[0,0,b,:] @ hid_w + hid_b
// bid 272..    : adaptive max pool (win=4) + dot dw_w -> h_feat[b,c,h]
//                one wave per row of 512 floats (measured best: multi-row
//                per wave regressed R2 +47us / R3 +19us). nt loads: feat is
//                streaming, no reuse (L3 retention measured ~nil in R4).
__global__ void k_pre_pool(const float* __restrict__ feat,
                           const float* __restrict__ dw_w,
                           const float* __restrict__ dw_b,
                           const float* __restrict__ convd_w,
                           const float* __restrict__ hidden,
                           const float* __restrict__ hid_w,
                           const float* __restrict__ hid_b,
                           float* __restrict__ hf, float* __restrict__ w2,
                           float* __restrict__ hv) {
  int bid = blockIdx.x, tid = threadIdx.x;
  if (bid < 256) {
    int f = bid;
#pragma unroll
    for (int q = 0; q < 5; ++q) {
      int r = q * 256 + tid;  // 0..1279 = c*5+t
      w2[(size_t)r * 256 + f] = convd_w[(size_t)f * 1280 + r];
    }
  } else if (bid < 272) {
    int b = bid - 256;
    const float* hh = hidden + b * HS_;
    float acc = hid_b[tid];
    for (int k = 0; k < HS_; ++k) acc = fmaf(hh[k], hid_w[k * AF_ + tid], acc);
    hv[b * AF_ + tid] = acc;
  } else {
    int wid = (bid - 272) * 4 + (tid >> 6);   // row id, 524288 rows
    int lane = tid & 63;
    const f4v* row = reinterpret_cast<const f4v*>(feat) + (size_t)wid * 128;
    f4v a = __builtin_nontemporal_load(row + lane);
    f4v b = __builtin_nontemporal_load(row + lane + 64);
    float m0 = fmaxf(fmaxf(a.x, a.y), fmaxf(a.z, a.w));
    float m1 = fmaxf(fmaxf(b.x, b.y), fmaxf(b.z, b.w));
    float p = m0 * dw_w[lane] + m1 * dw_w[lane + 64];
#pragma unroll
    for (int off = 32; off > 0; off >>= 1) p += __shfl_down(p, off, 64);
    if (lane == 0) hf[wid] = p + dw_b[0];
  }
}

// ---------------- L2: build s (tanh'd) + align. grid = B*(H/4), block 256 (f)
__global__ void k_sbuild(const float* __restrict__ pa,
                         const float* __restrict__ cv,
                         const float* __restrict__ hf,
                         const float* __restrict__ enc_w, const float* __restrict__ enc_b,
                         const float* __restrict__ conv_w, const float* __restrict__ conv_b,
                         const float* __restrict__ dcb_w, const float* __restrict__ dcb_b,
                         const float* __restrict__ hv,
                         const float* __restrict__ align_w, const float* __restrict__ align_b,
                         float* __restrict__ sbuf, float* __restrict__ alignv) {
  __shared__ float cat[2][H_];
  __shared__ float stats[4];     // mu0, inv_sigma0, mu1, inv_sigma1
  __shared__ float cbl[4][16];
  __shared__ float red[4][4];    // [wave][j]
  int bidx = blockIdx.x;
  int b = bidx >> 5;
  int h0 = (bidx & 31) * 4;
  int tid = threadIdx.x;

  if (tid < H_) {
    cat[0][tid] = pa[b * H_ + tid];
    float x = cv[b * H_ + tid];
    cat[1][tid] = fminf(fmaxf(x, 0.f), 1.f);
  }
  __syncthreads();
  if (tid < 2) {
    float s = 0.f, s2 = 0.f;
    for (int t = 0; t < H_; ++t) { float x = cat[tid][t]; s += x; s2 += x * x; }
    float mu = s / (float)H_;
    float var = s2 / (float)H_ - mu * mu;
    stats[tid * 2] = mu;
    stats[tid * 2 + 1] = rsqrtf(var + 1e-5f);
  }
  __syncthreads();
  {
    int ch = tid >> 7, t = tid & 127;     // all 256 threads
    cat[ch][t] = (cat[ch][t] - stats[ch * 2]) * stats[ch * 2 + 1];
  }
  __syncthreads();
  if (tid < 64) {            // cb[k, h0+j], kernel 15, pad 7
    int k = tid & 15, j = tid >> 4;
    int h = h0 + j;
    float acc = conv_b[k];
    for (int c2 = 0; c2 < 2; ++c2)
      for (int t = 0; t < 15; ++t) {
        int hh = h + t - 7;
        if (hh >= 0 && hh < H_) acc += cat[c2][hh] * conv_w[(k * 2 + c2) * 15 + t];
      }
    cbl[j][k] = acc;
  }
  __syncthreads();

  int f = tid;
  float base = enc_b[f] + dcb_b[f] + hv[b * AF_ + f];
  float acc[4];
#pragma unroll
  for (int j = 0; j < 4; ++j) {
    float a = base;
#pragma unroll
    for (int k = 0; k < 16; ++k) a = fmaf(cbl[j][k], dcb_w[k * AF_ + f], a);
    acc[j] = a;
  }
  const float* hfb = hf + (size_t)(b * C_) * H_ + h0;   // wave-uniform scalar loads
  for (int c = 0; c < C_; ++c) {
    float w = enc_w[c * AF_ + f];
#pragma unroll
    for (int j = 0; j < 4; ++j) acc[j] = fmaf(hfb[c * H_ + j], w, acc[j]);
  }
  float aw = align_w[f];
  int wvi = tid >> 6, lane = tid & 63;
#pragma unroll
  for (int j = 0; j < 4; ++j) {
    float s = tanhf(acc[j]);
    sbuf[(size_t)(b * H_ + h0 + j) * AF_ + f] = s;
    float v = s * aw;
#pragma unroll
    for (int off = 32; off > 0; off >>= 1) v += __shfl_down(v, off, 64);
    if (lane == 0) red[wvi][j] = v;
  }
  __syncthreads();
  if (tid < 4)
    alignv[b * H_ + h0 + tid] =
        red[0][tid] + red[1][tid] + red[2][tid] + red[3][tid] + align_b[0];
}

// ---------------- L3: dconv (bid<256) + softmax (bid 256..271). block 512.
// dconv: per (b, 8 h-rows): conv K=5 pad=2 over c + relu + maxpool4 -> dpool
// softmax: all 8 waves participate in barriers (inactive lanes: -1e30 / exp->0)
__global__ void k_sm_dconv(const float* __restrict__ sbuf, const float* __restrict__ w2,
                           const float* __restrict__ convd_b,
                           const float* __restrict__ alignv,
                           float* __restrict__ dpool, float* __restrict__ attn) {
  __shared__ float sw[12][AF_];
  __shared__ float part[8][AF_];
  __shared__ float redm[8], reds[8];
  int bidx = blockIdx.x;
  int tid = threadIdx.x;
  if (bidx < 256) {
    int b = bidx >> 4;
    int h0 = (bidx & 15) * 8;
    int f = tid & 255;
    int chalf = tid >> 8;
    for (int rr = chalf; rr < 12; rr += 2) {     // rows h0-2 .. h0+9, zero padded
      int h = h0 - 2 + rr;
      sw[rr][f] = (h >= 0 && h < H_) ? sbuf[(size_t)(b * H_ + h) * AF_ + f] : 0.f;
    }
    __syncthreads();
    float acc[8];
#pragma unroll
    for (int j = 0; j < 8; ++j) acc[j] = 0.f;
    int cstart = chalf * 128;
    for (int c = cstart; c < cstart + 128; ++c) {
      float sr[12];
#pragma unroll
      for (int rr = 0; rr < 12; ++rr) sr[rr] = sw[rr][c];   // LDS broadcast
      const float* wp = w2 + (size_t)c * 5 * 256 + f;
#pragma unroll
      for (int t = 0; t < 5; ++t) {
        float wv = wp[t * 256];                             // coalesced, L2-resident
#pragma unroll
        for (int j = 0; j < 8; ++j) acc[j] = fmaf(sr[j + t], wv, acc[j]);
      }
    }
    if (chalf == 1) {
#pragma unroll
      for (int j = 0; j < 8; ++j) part[j][f] = acc[j];
    }
    __syncthreads();
    if (chalf == 0) {
      float bias = convd_b[f];
#pragma unroll
      for (int j = 0; j < 8; ++j) acc[j] = fmaxf(acc[j] + part[j][f] + bias, 0.f);
      float p0 = fmaxf(fmaxf(acc[0], acc[1]), fmaxf(acc[2], acc[3]));
      float p1 = fmaxf(fmaxf(acc[4], acc[5]), fmaxf(acc[6], acc[7]));
      int m0 = h0 >> 2;
      dpool[(size_t)(b * 32 + m0) * AF_ + f] = p0;
      dpool[(size_t)(b * 32 + m0 + 1) * AF_ + f] = p1;
    }
  } else {
    int b = bidx - 256;
    float v = (tid < H_) ? alignv[b * H_ + tid] : -1e30f;
    float m = v;
#pragma unroll
    for (int off = 32; off > 0; off >>= 1) m = fmaxf(m, __shfl_down(m, off, 64));
    if ((tid & 63) == 0) redm[tid >> 6] = m;
    __syncthreads();
    float mm = redm[0];
#pragma unroll
    for (int q = 1; q < 8; ++q) mm = fmaxf(mm, redm[q]);
    float e = expf(v - mm);                    // inactive lanes: exp(-huge)=0
    float s = e;
#pragma unroll
    for (int off = 32; off > 0; off >>= 1) s += __shfl_down(s, off, 64);
    if ((tid & 63) == 0) reds[tid >> 6] = s;
    __syncthreads();
    float S = 0.f;
#pragma unroll
    for (int q = 0; q < 8; ++q) S += reds[q];  // exact: waves 2..7 add 0.0
    if (tid < H_) attn[b * H_ + tid] = e / S;
  }
}

// ---------------- L4: decision (bid<16) + context (bid 16..2063). block 256.
// decision: dh dot + relu, concat hh, dec matmul. Reads dpool (d_ws) — no
// overlap with context's ctx writes (dpool moved to d_ws for this reason).
// context: ctx[b,c,w] = sum_h feat[b,c,h,w]*attn[b,h]; reversed traversal,
// nt loads (streaming) + nt store.
__global__ void k_dec_ctx(const float* __restrict__ feat, const float* __restrict__ attn,
                          const float* __restrict__ dpool, const float* __restrict__ hidden,
                          const float* __restrict__ dh_w, const float* __restrict__ dh_b,
                          const float* __restrict__ dec_w, const float* __restrict__ dec_b,
                          float* __restrict__ dec_out, float* __restrict__ ctx) {
  __shared__ float at[H_];
  __shared__ float ddl[AF_];
  __shared__ float red[4];
  int bidx = blockIdx.x;
  int tid = threadIdx.x;
  if (bidx < 16) {
    int b = bidx;
    float acc = dh_b[0];
    for (int m = 0; m < 32; ++m)
      acc = fmaf(dpool[(size_t)(b * 32 + m) * AF_ + tid], dh_w[m], acc);
    ddl[tid] = fmaxf(acc, 0.f);
    __syncthreads();
    int col = tid >> 7, kk = tid & 127;
    float a = 0.f;
#pragma unroll
    for (int q = 0; q < 4; ++q) {
      int idx = kk + 128 * q;                // 0..511 over concat [hh(256), dd(256)]
      float x = (idx < 256) ? hidden[b * HS_ + idx] : ddl[idx - 256];
      a = fmaf(x, dec_w[idx * 2 + col], a);
    }
#pragma unroll
    for (int off = 32; off > 0; off >>= 1) a += __shfl_down(a, off, 64);
    if ((tid & 63) == 0) red[tid >> 6] = a;
    __syncthreads();
    if (tid < 2) dec_out[b * 2 + tid] = red[tid * 2] + red[tid * 2 + 1] + dec_b[tid];
  } else {
    int cb = 2063 - bidx;                    // reversed traversal (cb 2047..0)
    int b = cb >> 7;
    int c0 = (cb & 127) * 2;
    if (tid < H_) at[tid] = attn[b * H_ + tid];
    __syncthreads();
    int c = c0 + (tid >> 7);
    int wq = tid & 127;
    const f4v* f4 = reinterpret_cast<const f4v*>(feat) +
                    (size_t)(b * C_ + c) * H_ * (W_ / 4) + wq;
    f4v acc = (f4v){0.f, 0.f, 0.f, 0.f};
    for (int h = 0; h < H_; ++h) {
      f4v x = __builtin_nontemporal_load(f4 + (size_t)h * (W_ / 4));
      float a = at[h];
      acc.x += x.x * a; acc.y += x.y * a; acc.z += x.z * a; acc.w += x.w * a;
    }
    __builtin_nontemporal_store(acc,
        reinterpret_cast<f4v*>(ctx) + (size_t)(b * C_ + c) * (W_ / 4) + wq);
  }
}

extern "C" void kernel_launch(void* const* d_in, const int* in_sizes, int n_in,
                              void* d_out, int out_size, void* d_ws, size_t ws_size,
                              hipStream_t stream) {
  const float* feat    = (const float*)d_in[0];
  const float* pa      = (const float*)d_in[1];
  const float* cv      = (const float*)d_in[2];
  const float* hidden  = (const float*)d_in[3];
  const float* dw_w    = (const float*)d_in[4];
  const float* dw_b    = (const float*)d_in[5];
  const float* enc_w   = (const float*)d_in[6];
  const float* enc_b   = (const float*)d_in[7];
  const float* conv_w  = (const float*)d_in[8];
  const float* conv_b  = (const float*)d_in[9];
  const float* dcb_w   = (const float*)d_in[10];
  const float* dcb_b   = (const float*)d_in[11];
  const float* hid_w   = (const float*)d_in[12];
  const float* hid_b   = (const float*)d_in[13];
  const float* align_w = (const float*)d_in[14];
  const float* align_b = (const float*)d_in[15];
  const float* convd_w = (const float*)d_in[16];
  const float* convd_b = (const float*)d_in[17];
  const float* dh_w    = (const float*)d_in[18];
  const float* dh_b    = (const float*)d_in[19];
  const float* dec_w   = (const float*)d_in[20];
  const float* dec_b   = (const float*)d_in[21];

  float* out  = (float*)d_out;
  float* ctx  = out;                          // (B,C,W) = 2,097,152 floats
  float* attn = out + 2097152;                // (B,H)   = 2048
  float* dec  = out + 2097152 + 2048;         // (B,2)   = 32

  // Scratch: most lives in the ctx region (dead before L4's context writes);
  // dpool is in d_ws because decision reads it WHILE context writes ctx (L4).
  // dpool is fully rewritten every call before being read -> deterministic.
  float* hf     = ctx;                        // 524288  h_feat (B,C,H)
  float* sbuf   = ctx + 524288;               // 524288  s (B,H,AF) post-tanh
  float* hv     = ctx + 1179648;              // 4096    (B,AF)
  float* alignv = ctx + 1183744;              // 2048    (B,H)
  float* w2     = ctx + 1185792;              // 327680  transposed convd_w
  float* dpool  = (float*)d_ws;               // 131072  (B,32,AF)

  k_pre_pool<<<131344, 256, 0, stream>>>(feat, dw_w, dw_b, convd_w, hidden,
                                         hid_w, hid_b, hf, w2, hv);
  k_sbuild<<<512, 256, 0, stream>>>(pa, cv, hf, enc_w, enc_b, conv_w, conv_b,
                                    dcb_w, dcb_b, hv, align_w, align_b, sbuf, alignv);
  k_sm_dconv<<<272, 512, 0, stream>>>(sbuf, w2, convd_b, alignv, dpool, attn);
  k_dec_ctx<<<2064, 256, 0, stream>>>(feat, attn, dpool, hidden, dh_w, dh_b,
                                      dec_w, dec_b, dec, ctx);
}